// Round 3
// baseline (295.416 us; speedup 1.0000x reference)
//
#include <hip/hip_runtime.h>
#include <hip/hip_cooperative_groups.h>
#include <cmath>

#define TT 1024
#define BB 8
#define IND 512
#define NCH 32
#define CHL 32          // TT / NCH
#define EPSV 1e-8
#define OUTHALF ((size_t)TT * BB * 4096)

namespace cg = cooperative_groups;

// ============================ MEGA (cooperative) ==============================
// 512 blocks x 256 threads. Phases:
//   G:  projection GEMM, 16 rows/block  -> v,k,alpha(f64) in ws
//   0:  stage chunk (alpha,k,v) to LDS (persists!), chunk alpha-products -> cpA
//   1:  per-chunk partial C (f64 regs)  -> Csum
//   3:  exclusive prefix from Csum partials + final scan -> spk, mem
// LDS union: GEMM 26 KB | scan 32 KB -> 32 KB static.

union SharedMem {
    struct { float Wt[32][192]; float Xt[32][16]; } g;
    struct { double A[CHL][64]; double V[CHL][32]; float K[CHL][64]; } s;
};

__global__ __launch_bounds__(256, 2)
void mega(const float* __restrict__ x,
          const float* __restrict__ Wv, const float* __restrict__ bv,
          const float* __restrict__ Wk, const float* __restrict__ bk,
          const float* __restrict__ Wa, const float* __restrict__ ba,
          float* __restrict__ vBuf, float* __restrict__ kBuf,
          double* __restrict__ aBuf, double* __restrict__ cpA,
          double* __restrict__ Csum, float* __restrict__ outp)
{
    cg::grid_group grid = cg::this_grid();
    __shared__ SharedMem sh;
    const int tid = threadIdx.x;
    const int bid = blockIdx.x;

    // ---------------- phase G: GEMM, rows [bid*16, bid*16+16) -----------------
    {
        const int rowbase = bid * 16;
        const int c0 = tid & 63;                  // output col
        const int r0 = (tid >> 6) << 2;           // 4 rows per thread
        double av[4] = {}, ak[4] = {}, aa[4] = {};

        for (int ko = 0; ko < IND; ko += 32) {
            __syncthreads();
            if (tid < 192) {
                const float* src = (tid < 64  ? Wv + (size_t)tid * IND
                                  : tid < 128 ? Wk + (size_t)(tid - 64) * IND
                                  :             Wa + (size_t)(tid - 128) * IND) + ko;
                #pragma unroll
                for (int q = 0; q < 32; q += 4) {
                    float4 w4 = *(const float4*)(src + q);
                    sh.g.Wt[q+0][tid] = w4.x; sh.g.Wt[q+1][tid] = w4.y;
                    sh.g.Wt[q+2][tid] = w4.z; sh.g.Wt[q+3][tid] = w4.w;
                }
            }
            {
                int r  = tid & 15;
                int kq = (tid >> 4) << 1;         // 0,2,...,30
                float2 x2 = *(const float2*)(x + (size_t)(rowbase + r) * IND + ko + kq);
                sh.g.Xt[kq][r] = x2.x; sh.g.Xt[kq+1][r] = x2.y;
            }
            __syncthreads();

            float fv[4] = {}, fk[4] = {}, fa[4] = {};
            #pragma unroll
            for (int q = 0; q < 32; ++q) {
                float4 xa = *(const float4*)&sh.g.Xt[q][r0];   // wave-uniform
                float xr[4] = {xa.x, xa.y, xa.z, xa.w};
                float w0 = sh.g.Wt[q][c0], w1 = sh.g.Wt[q][c0 + 64], w2 = sh.g.Wt[q][c0 + 128];
                #pragma unroll
                for (int j = 0; j < 4; ++j) {
                    fv[j] = fmaf(xr[j], w0, fv[j]);
                    fk[j] = fmaf(xr[j], w1, fk[j]);
                    fa[j] = fmaf(xr[j], w2, fa[j]);
                }
            }
            #pragma unroll
            for (int j = 0; j < 4; ++j) { av[j] += fv[j]; ak[j] += fk[j]; aa[j] += fa[j]; }
        }
        #pragma unroll
        for (int j = 0; j < 4; ++j) {
            size_t r = (size_t)rowbase + r0 + j;
            vBuf[r * 64 + c0] = (float)(av[j] + (double)bv[c0]);
            kBuf[r * 64 + c0] = (float)(ak[j] + (double)bk[c0]);
            double z = aa[j] + (double)ba[c0];
            aBuf[r * 64 + c0] = 1.0 / (1.0 + exp(-z));
        }
    }
    grid.sync();

    // ---------------- scan-block role: (ch, b, dh) ----------------------------
    const int ch = bid >> 4;          // 32 chunks
    const int b  = (bid >> 1) & 7;    // 8 batches
    const int dh = bid & 1;           // d half (32 d's each)
    const int n  = tid & 63;
    const int w  = tid >> 6;          // 4 d-subgroups of 8

    // ---------------- stage chunk into LDS (persists through all phases) ------
    #pragma unroll
    for (int q = 0; q < 8; ++q) {
        int idx = q * 256 + tid;
        int t = idx >> 6, nn = idx & 63;
        int g = ((ch * CHL + t) * BB + b) * 64 + nn;
        sh.s.A[t][nn] = aBuf[g];
        sh.s.K[t][nn] = kBuf[g];
    }
    #pragma unroll
    for (int q = 0; q < 4; ++q) {
        int idx = q * 256 + tid;
        int t = idx >> 5, dd = idx & 31;
        sh.s.V[t][dd] = (double)vBuf[((ch * CHL + t) * BB + b) * 64 + dh * 32 + dd];
    }
    __syncthreads();

    // ---------------- phase 0: chunk alpha products ---------------------------
    if (dh == 0 && tid < 64) {
        double p = 1.0;
        #pragma unroll
        for (int t = 0; t < CHL; ++t) p *= sh.s.A[t][tid];
        cpA[ch * 512 + b * 64 + tid] = p;
    }
    grid.sync();

    // ---------------- phase 1: partial C over this chunk ----------------------
    double P0 = 1.0;
    for (int c = 0; c < ch; ++c) P0 *= cpA[c * 512 + b * 64 + n];
    double C[8];
    #pragma unroll
    for (int j = 0; j < 8; ++j) C[j] = 0.0;
    double P = P0;
    for (int t = 0; t < CHL; ++t) {
        P *= sh.s.A[t][n];
        double kd = (double)sh.s.K[t][n] / (P + EPSV);
        const double* vrow = &sh.s.V[t][w * 8];
        #pragma unroll
        for (int j = 0; j < 8; ++j) C[j] = fma(vrow[j], kd, C[j]);
    }
    {
        size_t cb = ((size_t)ch * 8 + b) * 4096 + (size_t)(dh * 32 + w * 8) * 64 + n;
        #pragma unroll
        for (int j = 0; j < 8; ++j) Csum[cb + j * 64] = C[j];
    }
    grid.sync();

    // ---------------- phase 3: prefix init + final scan + output --------------
    double Cacc[8];
    #pragma unroll
    for (int j = 0; j < 8; ++j) Cacc[j] = 0.0;
    for (int c = 0; c < ch; ++c) {
        size_t cb = ((size_t)c * 8 + b) * 4096 + (size_t)(dh * 32 + w * 8) * 64 + n;
        #pragma unroll
        for (int j = 0; j < 8; ++j) Cacc[j] += Csum[cb + j * 64];
    }
    float* spk = outp;
    float* mem = outp + OUTHALF;
    P = P0;
    for (int t = 0; t < CHL; ++t) {
        P *= sh.s.A[t][n];
        double kd = (double)sh.s.K[t][n] / (P + EPSV);
        const double* vrow = &sh.s.V[t][w * 8];
        size_t ob = ((size_t)((ch * CHL + t) * BB + b)) * 4096 + (size_t)(dh * 32 + w * 8) * 64 + n;
        #pragma unroll
        for (int j = 0; j < 8; ++j) {
            Cacc[j] = fma(vrow[j], kd, Cacc[j]);
            double S = P * Cacc[j];
            mem[ob + j * 64] = (float)S;
            spk[ob + j * 64] = (S > 1.0) ? 1.0f : 0.0f;
        }
    }
}

// ======================= FALLBACK (round-1 validated set) =====================
__global__ __launch_bounds__(256)
void k1_fb(const float* __restrict__ x,
           const float* __restrict__ Wv, const float* __restrict__ bv,
           const float* __restrict__ Wk, const float* __restrict__ bk,
           const float* __restrict__ Wa, const float* __restrict__ ba,
           float* __restrict__ vOut, float* __restrict__ kOut,
           double* __restrict__ aOut)
{
    __shared__ float sWt[64][192];
    __shared__ float sXt[64][16];
    const int tid = threadIdx.x;
    const int rowbase = blockIdx.x * 16;
    const int c0 = tid & 63;
    const int r0 = (tid >> 6) << 2;
    double a0[4] = {}, a1[4] = {}, a2[4] = {};

    for (int ko = 0; ko < IND; ko += 64) {
        __syncthreads();
        if (tid < 192) {
            const float* src = (tid < 64  ? Wv + (size_t)tid * IND
                              : tid < 128 ? Wk + (size_t)(tid - 64) * IND
                              :             Wa + (size_t)(tid - 128) * IND) + ko;
            #pragma unroll
            for (int q = 0; q < 64; q += 4) {
                float4 w4 = *(const float4*)(src + q);
                sWt[q+0][tid] = w4.x; sWt[q+1][tid] = w4.y;
                sWt[q+2][tid] = w4.z; sWt[q+3][tid] = w4.w;
            }
        }
        {
            int r  = tid & 15;
            int kq = (tid >> 4) << 2;
            float4 x4 = *(const float4*)(x + (size_t)(rowbase + r) * IND + ko + kq);
            sXt[kq+0][r] = x4.x; sXt[kq+1][r] = x4.y;
            sXt[kq+2][r] = x4.z; sXt[kq+3][r] = x4.w;
        }
        __syncthreads();
        float f0[4] = {}, f1[4] = {}, f2[4] = {};
        #pragma unroll
        for (int q = 0; q < 64; ++q) {
            float4 xv = *(const float4*)&sXt[q][r0];
            float xr[4] = {xv.x, xv.y, xv.z, xv.w};
            float w0 = sWt[q][c0], w1 = sWt[q][c0 + 64], w2 = sWt[q][c0 + 128];
            #pragma unroll
            for (int j = 0; j < 4; ++j) {
                f0[j] = fmaf(xr[j], w0, f0[j]);
                f1[j] = fmaf(xr[j], w1, f1[j]);
                f2[j] = fmaf(xr[j], w2, f2[j]);
            }
        }
        #pragma unroll
        for (int j = 0; j < 4; ++j) { a0[j] += f0[j]; a1[j] += f1[j]; a2[j] += f2[j]; }
    }
    #pragma unroll
    for (int j = 0; j < 4; ++j) {
        int r = rowbase + r0 + j;
        vOut[r * 64 + c0] = (float)(a0[j] + (double)bv[c0]);
        kOut[r * 64 + c0] = (float)(a1[j] + (double)bk[c0]);
        double z = a2[j] + (double)ba[c0];
        aOut[r * 64 + c0] = 1.0 / (1.0 + exp(-z));
    }
}

__global__ __launch_bounds__(256)
void k2a_fb(const double* __restrict__ alpha, double* __restrict__ cpA)
{
    int gt = blockIdx.x * 256 + threadIdx.x;
    int ch = gt >> 9, chain = gt & 511;
    double p = 1.0;
    int base = (ch * CHL) * 512 + chain;
    for (int i = 0; i < CHL; ++i) p *= alpha[base + i * 512];
    cpA[gt] = p;
}

__global__ __launch_bounds__(512)
void k2b_fb(double* __restrict__ cpA)
{
    int chain = threadIdx.x;
    double run = 1.0;
    for (int ch = 0; ch < NCH; ++ch) {
        double t = cpA[ch * 512 + chain];
        cpA[ch * 512 + chain] = run;
        run *= t;
    }
}

__global__ __launch_bounds__(256)
void k3_fb(const float* __restrict__ vIn, const float* __restrict__ kIn,
           const double* __restrict__ alpha, const double* __restrict__ cpA,
           double* __restrict__ Csum)
{
    __shared__ double sV[CHL * 64];
    const int tid = threadIdx.x;
    const int ch = blockIdx.x >> 3;
    const int b  = blockIdx.x & 7;
    #pragma unroll
    for (int q = 0; q < 8; ++q) {
        int idx = q * 256 + tid;
        int ti = idx >> 6, d = idx & 63;
        sV[idx] = (double)vIn[(((ch * CHL + ti) * BB) + b) * 64 + d];
    }
    __syncthreads();
    const int n = tid & 63;
    const int w = tid >> 6;
    double P = cpA[ch * 512 + b * 64 + n];
    double C[16];
    #pragma unroll
    for (int j = 0; j < 16; ++j) C[j] = 0.0;
    for (int i = 0; i < CHL; ++i) {
        int base = ((ch * CHL + i) * BB + b) * 64 + n;
        P *= alpha[base];
        double invp = 1.0 / (P + EPSV);
        double kd = (double)kIn[base] * invp;
        const double* vrow = &sV[i * 64 + w * 16];
        #pragma unroll
        for (int j = 0; j < 16; ++j) C[j] = fma(vrow[j], kd, C[j]);
    }
    size_t cb = ((size_t)ch * 8 + b) * 4096 + (size_t)w * 1024 + n;
    #pragma unroll
    for (int j = 0; j < 16; ++j) Csum[cb + j * 64] = C[j];
}

__global__ __launch_bounds__(256)
void k3b_fb(double* __restrict__ Csum)
{
    int s = blockIdx.x * 256 + threadIdx.x;
    int b = s >> 12, rest = s & 4095;
    double run = 0.0;
    for (int ch = 0; ch < NCH; ++ch) {
        size_t idx = ((size_t)ch * 8 + b) * 4096 + rest;
        double t = Csum[idx];
        Csum[idx] = run;
        run += t;
    }
}

__global__ __launch_bounds__(256)
void k4_fb(const float* __restrict__ vIn, const float* __restrict__ kIn,
           const double* __restrict__ alpha, const double* __restrict__ cpA,
           const double* __restrict__ Csum, float* __restrict__ outp)
{
    __shared__ double sV[CHL * 64];
    const int tid = threadIdx.x;
    const int ch = blockIdx.x >> 3;
    const int b  = blockIdx.x & 7;
    #pragma unroll
    for (int q = 0; q < 8; ++q) {
        int idx = q * 256 + tid;
        int ti = idx >> 6, d = idx & 63;
        sV[idx] = (double)vIn[(((ch * CHL + ti) * BB) + b) * 64 + d];
    }
    __syncthreads();
    const int n = tid & 63;
    const int w = tid >> 6;
    double P = cpA[ch * 512 + b * 64 + n];
    size_t cb = ((size_t)ch * 8 + b) * 4096 + (size_t)w * 1024 + n;
    double C[16];
    #pragma unroll
    for (int j = 0; j < 16; ++j) C[j] = Csum[cb + j * 64];
    float* spk = outp;
    float* mem = outp + OUTHALF;
    for (int i = 0; i < CHL; ++i) {
        int t = ch * CHL + i;
        int base = (t * BB + b) * 64 + n;
        P *= alpha[base];
        double invp = 1.0 / (P + EPSV);
        double kd = (double)kIn[base] * invp;
        const double* vrow = &sV[i * 64 + w * 16];
        size_t ob = ((size_t)t * BB + b) * 4096 + (size_t)w * 1024 + n;
        #pragma unroll
        for (int j = 0; j < 16; ++j) {
            C[j] = fma(vrow[j], kd, C[j]);
            double S = P * C[j];
            mem[ob + j * 64] = (float)S;
            spk[ob + j * 64] = (S > 1.0) ? 1.0f : 0.0f;
        }
    }
}

// ---------------- launch -------------------------------------------------------
extern "C" void kernel_launch(void* const* d_in, const int* in_sizes, int n_in,
                              void* d_out, int out_size, void* d_ws, size_t ws_size,
                              hipStream_t stream)
{
    const float* x  = (const float*)d_in[0];
    const float* Wv = (const float*)d_in[1];
    const float* bv = (const float*)d_in[2];
    const float* Wk = (const float*)d_in[3];
    const float* bk = (const float*)d_in[4];
    const float* Wa = (const float*)d_in[5];
    const float* ba = (const float*)d_in[6];
    float* out = (float*)d_out;

    char* ws = (char*)d_ws;
    float*  v     = (float*)(ws);                                   // 2 MB
    float*  kk    = (float*)(ws + (2u << 20));                      // 2 MB
    double* alpha = (double*)(ws + (4u << 20));                     // 4 MB
    double* cpA   = (double*)(ws + (8u << 20));                     // 128 KB
    double* Csum  = (double*)(ws + (9u << 20));                     // 8 MB

    void* args[] = { (void*)&x, (void*)&Wv, (void*)&bv, (void*)&Wk, (void*)&bk,
                     (void*)&Wa, (void*)&ba, (void*)&v, (void*)&kk, (void*)&alpha,
                     (void*)&cpA, (void*)&Csum, (void*)&out };
    hipError_t e = hipLaunchCooperativeKernel((const void*)mega, dim3(512), dim3(256),
                                              args, 0, stream);
    if (e != hipSuccess) {
        (void)hipGetLastError();   // clear sticky error, use validated split path
        hipLaunchKernelGGL(k1_fb,  dim3(512), dim3(256), 0, stream,
                           x, Wv, bv, Wk, bk, Wa, ba, v, kk, alpha);
        hipLaunchKernelGGL(k2a_fb, dim3(64),  dim3(256), 0, stream, alpha, cpA);
        hipLaunchKernelGGL(k2b_fb, dim3(1),   dim3(512), 0, stream, cpA);
        hipLaunchKernelGGL(k3_fb,  dim3(256), dim3(256), 0, stream, v, kk, alpha, cpA, Csum);
        hipLaunchKernelGGL(k3b_fb, dim3(128), dim3(256), 0, stream, Csum);
        hipLaunchKernelGGL(k4_fb,  dim3(256), dim3(256), 0, stream, v, kk, alpha, cpA, Csum, out);
    }
}

// Round 4
// 142.708 us; speedup vs baseline: 2.0701x; 2.0701x over previous
//
#include <hip/hip_runtime.h>
#include <cmath>

#define TT 1024
#define BB 8
#define IND 512
#define NCH 32
#define CHL 32          // TT / NCH
#define EPSV 1e-8
#define OUTHALF ((size_t)TT * BB * 4096)

// ---------------- K1: projections v,k,alpha (f32 GEMM, 8 rows/thread) ----------
// alpha stored as f32 (matches np's f32 sigmoid more closely, halves traffic)
__global__ __launch_bounds__(256)
void k1_proj(const float* __restrict__ x,
             const float* __restrict__ Wv, const float* __restrict__ bv,
             const float* __restrict__ Wk, const float* __restrict__ bk,
             const float* __restrict__ Wa, const float* __restrict__ ba,
             float* __restrict__ vOut, float* __restrict__ kOut,
             float* __restrict__ aOut)
{
    __shared__ float sWt[64][192];   // 48 KB transposed weight chunk (3 mats)
    __shared__ float sXt[64][32];    // 8 KB  transposed x chunk (32 rows)
    const int tid = threadIdx.x;
    const int rowbase = blockIdx.x * 32;          // 256 blocks * 32 rows
    const int c0 = tid & 63;                      // output col
    const int r0 = (tid >> 6) << 3;               // 8 rows per thread (wave-uniform)
    double av[8] = {}, ak[8] = {}, aa[8] = {};

    for (int ko = 0; ko < IND; ko += 64) {
        __syncthreads();
        if (tid < 192) {
            const float* src = (tid < 64  ? Wv + (size_t)tid * IND
                              : tid < 128 ? Wk + (size_t)(tid - 64) * IND
                              :             Wa + (size_t)(tid - 128) * IND) + ko;
            #pragma unroll
            for (int q = 0; q < 64; q += 4) {
                float4 w4 = *(const float4*)(src + q);
                sWt[q+0][tid] = w4.x; sWt[q+1][tid] = w4.y;
                sWt[q+2][tid] = w4.z; sWt[q+3][tid] = w4.w;
            }
        }
        {
            const int r  = tid & 31;
            const int kq = (tid >> 5) << 3;       // 0,8,...,56
            const float* xs = x + (size_t)(rowbase + r) * IND + ko + kq;
            float4 xa = *(const float4*)xs;
            float4 xb = *(const float4*)(xs + 4);
            sXt[kq+0][r] = xa.x; sXt[kq+1][r] = xa.y; sXt[kq+2][r] = xa.z; sXt[kq+3][r] = xa.w;
            sXt[kq+4][r] = xb.x; sXt[kq+5][r] = xb.y; sXt[kq+6][r] = xb.z; sXt[kq+7][r] = xb.w;
        }
        __syncthreads();

        float fv[8] = {}, fk[8] = {}, fa[8] = {};
        #pragma unroll
        for (int q = 0; q < 64; ++q) {
            float4 xa = *(const float4*)&sXt[q][r0];      // wave-uniform broadcast
            float4 xb = *(const float4*)&sXt[q][r0 + 4];
            float xr[8] = {xa.x, xa.y, xa.z, xa.w, xb.x, xb.y, xb.z, xb.w};
            float w0 = sWt[q][c0], w1 = sWt[q][c0 + 64], w2 = sWt[q][c0 + 128];
            #pragma unroll
            for (int j = 0; j < 8; ++j) {
                fv[j] = fmaf(xr[j], w0, fv[j]);
                fk[j] = fmaf(xr[j], w1, fk[j]);
                fa[j] = fmaf(xr[j], w2, fa[j]);
            }
        }
        #pragma unroll
        for (int j = 0; j < 8; ++j) { av[j] += fv[j]; ak[j] += fk[j]; aa[j] += fa[j]; }
    }

    #pragma unroll
    for (int j = 0; j < 8; ++j) {
        size_t r = (size_t)rowbase + r0 + j;
        vOut[r * 64 + c0] = (float)(av[j] + (double)bv[c0]);
        kOut[r * 64 + c0] = (float)(ak[j] + (double)bk[c0]);
        double z = aa[j] + (double)ba[c0];
        aOut[r * 64 + c0] = (float)(1.0 / (1.0 + exp(-z)));
    }
}

// ---------------- KPF: exclusive chunk cumprod prefix, one kernel --------------
// 512 independent chains; coalesced column reads of alpha from L2/L3.
__global__ __launch_bounds__(64)
void kPF(const float* __restrict__ alpha, double* __restrict__ cpA)
{
    int chain = blockIdx.x * 64 + threadIdx.x;    // 8 blocks x 64 = 512 chains
    double run = 1.0;
    for (int ch = 0; ch < NCH; ++ch) {
        cpA[ch * 512 + chain] = run;              // exclusive prefix
        double p = 1.0;
        #pragma unroll
        for (int t = 0; t < CHL; ++t)
            p *= (double)alpha[(ch * CHL + t) * 512 + chain];
        run *= p;                                 // same association as k2a+k2b
    }
}

// ---------------- K3: per-chunk partial C sums (512 blocks, d-half split) ------
__global__ __launch_bounds__(256)
void k3_csum(const float* __restrict__ vIn, const float* __restrict__ kIn,
             const float* __restrict__ alpha, const double* __restrict__ cpA,
             double* __restrict__ Csum)
{
    __shared__ float  sA[CHL][64];                // 8 KB
    __shared__ float  sK[CHL][64];                // 8 KB
    __shared__ double sV[CHL][32];                // 8 KB
    const int tid = threadIdx.x;
    const int ch = blockIdx.x >> 4;
    const int b  = (blockIdx.x >> 1) & 7;
    const int dh = blockIdx.x & 1;
    #pragma unroll
    for (int q = 0; q < 8; ++q) {
        int idx = q * 256 + tid;
        int t = idx >> 6, nn = idx & 63;
        int g = ((ch * CHL + t) * BB + b) * 64 + nn;
        sA[t][nn] = alpha[g];
        sK[t][nn] = kIn[g];
    }
    #pragma unroll
    for (int q = 0; q < 4; ++q) {
        int idx = q * 256 + tid;
        int t = idx >> 5, dd = idx & 31;
        sV[t][dd] = (double)vIn[((ch * CHL + t) * BB + b) * 64 + dh * 32 + dd];
    }
    __syncthreads();
    const int n = tid & 63;
    const int w = tid >> 6;
    double P = cpA[ch * 512 + b * 64 + n];
    double C[8] = {};
    for (int t = 0; t < CHL; ++t) {
        P *= (double)sA[t][n];
        double kd = (double)sK[t][n] / (P + EPSV);
        const double* vr = &sV[t][w * 8];
        #pragma unroll
        for (int j = 0; j < 8; ++j) C[j] = fma(vr[j], kd, C[j]);
    }
    size_t cb = ((size_t)ch * 8 + b) * 4096 + (size_t)(dh * 32 + w * 8) * 64 + n;
    #pragma unroll
    for (int j = 0; j < 8; ++j) Csum[cb + j * 64] = C[j];
}

// ---------------- K3b: exclusive prefix sum of chunk partials ------------------
__global__ __launch_bounds__(256)
void k3b_prefix(double* __restrict__ Csum)
{
    int s = blockIdx.x * 256 + threadIdx.x;       // 32768 chains
    int b = s >> 12, rest = s & 4095;
    double run = 0.0;
    for (int ch = 0; ch < NCH; ++ch) {
        size_t idx = ((size_t)ch * 8 + b) * 4096 + rest;
        double t = Csum[idx];
        Csum[idx] = run;
        run += t;
    }
}

// ---------------- K4: main scan, nontemporal output stores ---------------------
__global__ __launch_bounds__(256)
void k4_scan(const float* __restrict__ vIn, const float* __restrict__ kIn,
             const float* __restrict__ alpha, const double* __restrict__ cpA,
             const double* __restrict__ Csum, float* __restrict__ outp)
{
    __shared__ float  sA[CHL][64];
    __shared__ float  sK[CHL][64];
    __shared__ double sV[CHL][32];
    const int tid = threadIdx.x;
    const int ch = blockIdx.x >> 4;
    const int b  = (blockIdx.x >> 1) & 7;
    const int dh = blockIdx.x & 1;
    #pragma unroll
    for (int q = 0; q < 8; ++q) {
        int idx = q * 256 + tid;
        int t = idx >> 6, nn = idx & 63;
        int g = ((ch * CHL + t) * BB + b) * 64 + nn;
        sA[t][nn] = alpha[g];
        sK[t][nn] = kIn[g];
    }
    #pragma unroll
    for (int q = 0; q < 4; ++q) {
        int idx = q * 256 + tid;
        int t = idx >> 5, dd = idx & 31;
        sV[t][dd] = (double)vIn[((ch * CHL + t) * BB + b) * 64 + dh * 32 + dd];
    }
    __syncthreads();
    const int n = tid & 63;
    const int w = tid >> 6;
    double P = cpA[ch * 512 + b * 64 + n];
    size_t cb = ((size_t)ch * 8 + b) * 4096 + (size_t)(dh * 32 + w * 8) * 64 + n;
    double C[8];
    #pragma unroll
    for (int j = 0; j < 8; ++j) C[j] = Csum[cb + j * 64];

    float* spk = outp;
    float* mem = outp + OUTHALF;
    for (int t = 0; t < CHL; ++t) {
        P *= (double)sA[t][n];
        double kd = (double)sK[t][n] / (P + EPSV);
        const double* vr = &sV[t][w * 8];
        size_t ob = ((size_t)((ch * CHL + t) * BB + b)) * 4096
                  + (size_t)(dh * 32 + w * 8) * 64 + n;
        #pragma unroll
        for (int j = 0; j < 8; ++j) {
            C[j] = fma(vr[j], kd, C[j]);
            double S = P * C[j];
            __builtin_nontemporal_store((float)S, &mem[ob + j * 64]);
            __builtin_nontemporal_store((S > 1.0) ? 1.0f : 0.0f, &spk[ob + j * 64]);
        }
    }
}

// ---------------- launch -------------------------------------------------------
extern "C" void kernel_launch(void* const* d_in, const int* in_sizes, int n_in,
                              void* d_out, int out_size, void* d_ws, size_t ws_size,
                              hipStream_t stream)
{
    const float* x  = (const float*)d_in[0];
    const float* Wv = (const float*)d_in[1];
    const float* bv = (const float*)d_in[2];
    const float* Wk = (const float*)d_in[3];
    const float* bk = (const float*)d_in[4];
    const float* Wa = (const float*)d_in[5];
    const float* ba = (const float*)d_in[6];
    float* out = (float*)d_out;

    char* ws = (char*)d_ws;
    float*  v     = (float*)(ws);                                   // 2 MB
    float*  kk    = (float*)(ws + (2u << 20));                      // 2 MB
    float*  alpha = (float*)(ws + (4u << 20));                      // 2 MB
    double* cpA   = (double*)(ws + (6u << 20));                     // 128 KB
    double* Csum  = (double*)(ws + (7u << 20));                     // 8 MB

    hipLaunchKernelGGL(k1_proj,    dim3(256), dim3(256), 0, stream,
                       x, Wv, bv, Wk, bk, Wa, ba, v, kk, alpha);
    hipLaunchKernelGGL(kPF,        dim3(8),   dim3(64),  0, stream, alpha, cpA);
    hipLaunchKernelGGL(k3_csum,    dim3(512), dim3(256), 0, stream,
                       v, kk, alpha, cpA, Csum);
    hipLaunchKernelGGL(k3b_prefix, dim3(128), dim3(256), 0, stream, Csum);
    hipLaunchKernelGGL(k4_scan,    dim3(512), dim3(256), 0, stream,
                       v, kk, alpha, cpA, Csum, out);
}

// Round 5
// 130.382 us; speedup vs baseline: 2.2658x; 1.0945x over previous
//
#include <hip/hip_runtime.h>
#include <cmath>

#define TT 1024
#define BB 8
#define IND 512
#define NCH 32
#define CHL 32          // TT / NCH
#define EPSV 1e-8
#define OUTHALF ((size_t)TT * BB * 4096)

// ---------------- K1: projections v,k,alpha (round-1 exact, alpha f32 out) -----
__global__ __launch_bounds__(256)
void k1_proj(const float* __restrict__ x,
             const float* __restrict__ Wv, const float* __restrict__ bv,
             const float* __restrict__ Wk, const float* __restrict__ bk,
             const float* __restrict__ Wa, const float* __restrict__ ba,
             float* __restrict__ vOut, float* __restrict__ kOut,
             float* __restrict__ aOut)
{
    __shared__ float sWt[64][192];   // 48 KB, transposed weight chunk
    __shared__ float sXt[64][16];    // 4 KB,  transposed x chunk
    const int tid = threadIdx.x;
    const int rowbase = blockIdx.x * 16;          // 512 blocks * 16 rows = 8192
    const int c0 = tid & 63;                      // output col within each matrix
    const int r0 = (tid >> 6) << 2;               // 4 rows per thread
    double a0[4] = {}, a1[4] = {}, a2[4] = {};

    for (int ko = 0; ko < IND; ko += 64) {
        __syncthreads();
        if (tid < 192) {
            const float* src = (tid < 64  ? Wv + (size_t)tid * IND
                              : tid < 128 ? Wk + (size_t)(tid - 64) * IND
                              :             Wa + (size_t)(tid - 128) * IND) + ko;
            #pragma unroll
            for (int q = 0; q < 64; q += 4) {
                float4 w4 = *(const float4*)(src + q);
                sWt[q+0][tid] = w4.x; sWt[q+1][tid] = w4.y;
                sWt[q+2][tid] = w4.z; sWt[q+3][tid] = w4.w;
            }
        }
        {
            int r  = tid & 15;
            int kq = (tid >> 4) << 2;
            float4 x4 = *(const float4*)(x + (size_t)(rowbase + r) * IND + ko + kq);
            sXt[kq+0][r] = x4.x; sXt[kq+1][r] = x4.y;
            sXt[kq+2][r] = x4.z; sXt[kq+3][r] = x4.w;
        }
        __syncthreads();

        float f0[4] = {}, f1[4] = {}, f2[4] = {};
        #pragma unroll
        for (int q = 0; q < 64; ++q) {
            float4 xv = *(const float4*)&sXt[q][r0];   // wave-uniform broadcast
            float w0 = sWt[q][c0], w1 = sWt[q][c0 + 64], w2 = sWt[q][c0 + 128];
            f0[0] = fmaf(xv.x, w0, f0[0]); f1[0] = fmaf(xv.x, w1, f1[0]); f2[0] = fmaf(xv.x, w2, f2[0]);
            f0[1] = fmaf(xv.y, w0, f0[1]); f1[1] = fmaf(xv.y, w1, f1[1]); f2[1] = fmaf(xv.y, w2, f2[1]);
            f0[2] = fmaf(xv.z, w0, f0[2]); f1[2] = fmaf(xv.z, w1, f1[2]); f2[2] = fmaf(xv.z, w2, f2[2]);
            f0[3] = fmaf(xv.w, w0, f0[3]); f1[3] = fmaf(xv.w, w1, f1[3]); f2[3] = fmaf(xv.w, w2, f2[3]);
        }
        #pragma unroll
        for (int i = 0; i < 4; ++i) { a0[i] += f0[i]; a1[i] += f1[i]; a2[i] += f2[i]; }
    }

    #pragma unroll
    for (int i = 0; i < 4; ++i) {
        int r = rowbase + r0 + i;
        vOut[r * 64 + c0] = (float)(a0[i] + (double)bv[c0]);
        kOut[r * 64 + c0] = (float)(a1[i] + (double)bk[c0]);
        double z = a2[i] + (double)ba[c0];
        aOut[r * 64 + c0] = (float)(1.0 / (1.0 + exp(-z)));
    }
}

// ---------------- KPF: exclusive chunk cumprod prefix (replaces k2a+k2b) -------
// 512 independent chains; same association as k2a (inner t-product) then k2b.
__global__ __launch_bounds__(64)
void kPF(const float* __restrict__ alpha, double* __restrict__ cpA)
{
    int chain = blockIdx.x * 64 + threadIdx.x;    // 8 blocks x 64 = 512 chains
    double run = 1.0;
    for (int ch = 0; ch < NCH; ++ch) {
        cpA[ch * 512 + chain] = run;              // exclusive prefix
        double p = 1.0;
        #pragma unroll
        for (int t = 0; t < CHL; ++t)
            p *= (double)alpha[(ch * CHL + t) * 512 + chain];
        run *= p;
    }
}

// ---------------- K3: per-chunk partial C sums (round-1 exact, alpha f32) ------
__global__ __launch_bounds__(256)
void k3_csum(const float* __restrict__ vIn, const float* __restrict__ kIn,
             const float* __restrict__ alpha, const double* __restrict__ cpA,
             double* __restrict__ Csum)
{
    __shared__ double sV[CHL * 64];               // 16 KB
    const int tid = threadIdx.x;
    const int ch = blockIdx.x >> 3;
    const int b  = blockIdx.x & 7;
    #pragma unroll
    for (int q = 0; q < 8; ++q) {
        int idx = q * 256 + tid;
        int ti = idx >> 6, d = idx & 63;
        sV[idx] = (double)vIn[(((ch * CHL + ti) * BB) + b) * 64 + d];
    }
    __syncthreads();
    const int n = tid & 63;
    const int w = tid >> 6;
    double P = cpA[ch * 512 + b * 64 + n];
    double C[16];
    #pragma unroll
    for (int j = 0; j < 16; ++j) C[j] = 0.0;
    for (int i = 0; i < CHL; ++i) {
        int base = ((ch * CHL + i) * BB + b) * 64 + n;
        P *= (double)alpha[base];
        double invp = 1.0 / (P + EPSV);
        double kd = (double)kIn[base] * invp;
        const double* vrow = &sV[i * 64 + w * 16];
        #pragma unroll
        for (int j = 0; j < 16; ++j) C[j] = fma(vrow[j], kd, C[j]);
    }
    size_t cb = ((size_t)ch * 8 + b) * 4096 + (size_t)w * 1024 + n;
    #pragma unroll
    for (int j = 0; j < 16; ++j) Csum[cb + j * 64] = C[j];
}

// ---------------- K3b: exclusive prefix sum of chunk partials (round-1 exact) --
__global__ __launch_bounds__(256)
void k3b_prefix(double* __restrict__ Csum)
{
    int s = blockIdx.x * 256 + threadIdx.x;       // 32768 chains
    int b = s >> 12, rest = s & 4095;
    double run = 0.0;
    for (int ch = 0; ch < NCH; ++ch) {
        size_t idx = ((size_t)ch * 8 + b) * 4096 + rest;
        double t = Csum[idx];
        Csum[idx] = run;
        run += t;
    }
}

// ---------------- K4: main scan (round-1 exact, alpha f32, plain stores) -------
__global__ __launch_bounds__(256)
void k4_scan(const float* __restrict__ vIn, const float* __restrict__ kIn,
             const float* __restrict__ alpha, const double* __restrict__ cpA,
             const double* __restrict__ Csum, float* __restrict__ outp)
{
    __shared__ double sV[CHL * 64];
    const int tid = threadIdx.x;
    const int ch = blockIdx.x >> 3;
    const int b  = blockIdx.x & 7;
    #pragma unroll
    for (int q = 0; q < 8; ++q) {
        int idx = q * 256 + tid;
        int ti = idx >> 6, d = idx & 63;
        sV[idx] = (double)vIn[(((ch * CHL + ti) * BB) + b) * 64 + d];
    }
    __syncthreads();
    const int n = tid & 63;
    const int w = tid >> 6;
    double P = cpA[ch * 512 + b * 64 + n];
    size_t cb = ((size_t)ch * 8 + b) * 4096 + (size_t)w * 1024 + n;
    double C[16];
    #pragma unroll
    for (int j = 0; j < 16; ++j) C[j] = Csum[cb + j * 64];

    float* spk = outp;
    float* mem = outp + OUTHALF;
    for (int i = 0; i < CHL; ++i) {
        int t = ch * CHL + i;
        int base = (t * BB + b) * 64 + n;
        P *= (double)alpha[base];
        double invp = 1.0 / (P + EPSV);
        double kd = (double)kIn[base] * invp;
        const double* vrow = &sV[i * 64 + w * 16];
        size_t ob = ((size_t)t * BB + b) * 4096 + (size_t)w * 1024 + n;
        #pragma unroll
        for (int j = 0; j < 16; ++j) {
            C[j] = fma(vrow[j], kd, C[j]);
            double S = P * C[j];
            mem[ob + j * 64] = (float)S;
            spk[ob + j * 64] = (S > 1.0) ? 1.0f : 0.0f;
        }
    }
}

// ---------------- launch -------------------------------------------------------
extern "C" void kernel_launch(void* const* d_in, const int* in_sizes, int n_in,
                              void* d_out, int out_size, void* d_ws, size_t ws_size,
                              hipStream_t stream)
{
    const float* x  = (const float*)d_in[0];
    const float* Wv = (const float*)d_in[1];
    const float* bv = (const float*)d_in[2];
    const float* Wk = (const float*)d_in[3];
    const float* bk = (const float*)d_in[4];
    const float* Wa = (const float*)d_in[5];
    const float* ba = (const float*)d_in[6];
    float* out = (float*)d_out;

    char* ws = (char*)d_ws;
    float*  v     = (float*)(ws);                                   // 2 MB
    float*  kk    = (float*)(ws + (2u << 20));                      // 2 MB
    float*  alpha = (float*)(ws + (4u << 20));                      // 2 MB
    double* cpA   = (double*)(ws + (6u << 20));                     // 128 KB
    double* Csum  = (double*)(ws + (7u << 20));                     // 8 MB

    hipLaunchKernelGGL(k1_proj,    dim3(512), dim3(256), 0, stream,
                       x, Wv, bv, Wk, bk, Wa, ba, v, kk, alpha);
    hipLaunchKernelGGL(kPF,        dim3(8),   dim3(64),  0, stream, alpha, cpA);
    hipLaunchKernelGGL(k3_csum,    dim3(256), dim3(256), 0, stream,
                       v, kk, alpha, cpA, Csum);
    hipLaunchKernelGGL(k3b_prefix, dim3(128), dim3(256), 0, stream, Csum);
    hipLaunchKernelGGL(k4_scan,    dim3(256), dim3(256), 0, stream,
                       v, kk, alpha, cpA, Csum, out);
}

// Round 6
// 117.798 us; speedup vs baseline: 2.5078x; 1.1068x over previous
//
#include <hip/hip_runtime.h>
#include <cmath>

#define TT 1024
#define BB 8
#define IND 512
#define NCH 32
#define CHL 32          // TT / NCH
#define EPSV 1e-8
#define OUTHALF ((size_t)TT * BB * 4096)

// ---------------- K1: projections v,k,alpha (round-1 exact, alpha f32 out) -----
__global__ __launch_bounds__(256)
void k1_proj(const float* __restrict__ x,
             const float* __restrict__ Wv, const float* __restrict__ bv,
             const float* __restrict__ Wk, const float* __restrict__ bk,
             const float* __restrict__ Wa, const float* __restrict__ ba,
             float* __restrict__ vOut, float* __restrict__ kOut,
             float* __restrict__ aOut)
{
    __shared__ float sWt[64][192];   // 48 KB, transposed weight chunk
    __shared__ float sXt[64][16];    // 4 KB,  transposed x chunk
    const int tid = threadIdx.x;
    const int rowbase = blockIdx.x * 16;          // 512 blocks * 16 rows = 8192
    const int c0 = tid & 63;                      // output col within each matrix
    const int r0 = (tid >> 6) << 2;               // 4 rows per thread
    double a0[4] = {}, a1[4] = {}, a2[4] = {};

    for (int ko = 0; ko < IND; ko += 64) {
        __syncthreads();
        if (tid < 192) {
            const float* src = (tid < 64  ? Wv + (size_t)tid * IND
                              : tid < 128 ? Wk + (size_t)(tid - 64) * IND
                              :             Wa + (size_t)(tid - 128) * IND) + ko;
            #pragma unroll
            for (int q = 0; q < 64; q += 4) {
                float4 w4 = *(const float4*)(src + q);
                sWt[q+0][tid] = w4.x; sWt[q+1][tid] = w4.y;
                sWt[q+2][tid] = w4.z; sWt[q+3][tid] = w4.w;
            }
        }
        {
            int r  = tid & 15;
            int kq = (tid >> 4) << 2;
            float4 x4 = *(const float4*)(x + (size_t)(rowbase + r) * IND + ko + kq);
            sXt[kq+0][r] = x4.x; sXt[kq+1][r] = x4.y;
            sXt[kq+2][r] = x4.z; sXt[kq+3][r] = x4.w;
        }
        __syncthreads();

        float f0[4] = {}, f1[4] = {}, f2[4] = {};
        #pragma unroll
        for (int q = 0; q < 64; ++q) {
            float4 xv = *(const float4*)&sXt[q][r0];   // wave-uniform broadcast
            float w0 = sWt[q][c0], w1 = sWt[q][c0 + 64], w2 = sWt[q][c0 + 128];
            f0[0] = fmaf(xv.x, w0, f0[0]); f1[0] = fmaf(xv.x, w1, f1[0]); f2[0] = fmaf(xv.x, w2, f2[0]);
            f0[1] = fmaf(xv.y, w0, f0[1]); f1[1] = fmaf(xv.y, w1, f1[1]); f2[1] = fmaf(xv.y, w2, f2[1]);
            f0[2] = fmaf(xv.z, w0, f0[2]); f1[2] = fmaf(xv.z, w1, f1[2]); f2[2] = fmaf(xv.z, w2, f2[2]);
            f0[3] = fmaf(xv.w, w0, f0[3]); f1[3] = fmaf(xv.w, w1, f1[3]); f2[3] = fmaf(xv.w, w2, f2[3]);
        }
        #pragma unroll
        for (int i = 0; i < 4; ++i) { a0[i] += f0[i]; a1[i] += f1[i]; a2[i] += f2[i]; }
    }

    #pragma unroll
    for (int i = 0; i < 4; ++i) {
        int r = rowbase + r0 + i;
        vOut[r * 64 + c0] = (float)(a0[i] + (double)bv[c0]);
        kOut[r * 64 + c0] = (float)(a1[i] + (double)bk[c0]);
        double z = a2[i] + (double)ba[c0];
        aOut[r * 64 + c0] = (float)(1.0 / (1.0 + exp(-z)));
    }
}

// ---------------- K2a: per-chunk alpha products (64 blocks, full TLP) ----------
__global__ __launch_bounds__(256)
void k2a_chunkprod(const float* __restrict__ alpha, double* __restrict__ cpA)
{
    int gt = blockIdx.x * 256 + threadIdx.x;      // 16384 = 32 chunks * 512 chains
    int ch = gt >> 9, chain = gt & 511;
    double p = 1.0;
    int base = (ch * CHL) * 512 + chain;
    #pragma unroll
    for (int i = 0; i < CHL; ++i) p *= (double)alpha[base + i * 512];
    cpA[gt] = p;
}

// ---------------- K2b: exclusive prefix product, register-staged ---------------
// Load all 32 chunk products first (independent, pipelined), then scan in regs.
__global__ __launch_bounds__(512)
void k2b_prefix(double* __restrict__ cpA)
{
    int chain = threadIdx.x;                      // 512 threads, 1 block
    double vals[NCH];
    #pragma unroll
    for (int ch = 0; ch < NCH; ++ch) vals[ch] = cpA[ch * 512 + chain];
    double run = 1.0;
    #pragma unroll
    for (int ch = 0; ch < NCH; ++ch) {
        cpA[ch * 512 + chain] = run;
        run *= vals[ch];
    }
}

// ---------------- K3: per-chunk partial C sums (round-1 exact, alpha f32) ------
__global__ __launch_bounds__(256)
void k3_csum(const float* __restrict__ vIn, const float* __restrict__ kIn,
             const float* __restrict__ alpha, const double* __restrict__ cpA,
             double* __restrict__ Csum)
{
    __shared__ double sV[CHL * 64];               // 16 KB
    const int tid = threadIdx.x;
    const int ch = blockIdx.x >> 3;
    const int b  = blockIdx.x & 7;
    #pragma unroll
    for (int q = 0; q < 8; ++q) {
        int idx = q * 256 + tid;
        int ti = idx >> 6, d = idx & 63;
        sV[idx] = (double)vIn[(((ch * CHL + ti) * BB) + b) * 64 + d];
    }
    __syncthreads();
    const int n = tid & 63;
    const int w = tid >> 6;
    double P = cpA[ch * 512 + b * 64 + n];
    double C[16];
    #pragma unroll
    for (int j = 0; j < 16; ++j) C[j] = 0.0;
    for (int i = 0; i < CHL; ++i) {
        int base = ((ch * CHL + i) * BB + b) * 64 + n;
        P *= (double)alpha[base];
        double invp = 1.0 / (P + EPSV);
        double kd = (double)kIn[base] * invp;
        const double* vrow = &sV[i * 64 + w * 16];
        #pragma unroll
        for (int j = 0; j < 16; ++j) C[j] = fma(vrow[j], kd, C[j]);
    }
    size_t cb = ((size_t)ch * 8 + b) * 4096 + (size_t)w * 1024 + n;
    #pragma unroll
    for (int j = 0; j < 16; ++j) Csum[cb + j * 64] = C[j];
}

// ---------------- K3b: exclusive prefix sum, register-staged -------------------
__global__ __launch_bounds__(256)
void k3b_prefix(double* __restrict__ Csum)
{
    int s = blockIdx.x * 256 + threadIdx.x;       // 32768 chains
    int b = s >> 12, rest = s & 4095;
    double vals[NCH];
    #pragma unroll
    for (int ch = 0; ch < NCH; ++ch)
        vals[ch] = Csum[((size_t)ch * 8 + b) * 4096 + rest];
    double run = 0.0;
    #pragma unroll
    for (int ch = 0; ch < NCH; ++ch) {
        Csum[((size_t)ch * 8 + b) * 4096 + rest] = run;
        run += vals[ch];
    }
}

// ---------------- K4: main scan (round-1 exact, alpha f32, plain stores) -------
__global__ __launch_bounds__(256)
void k4_scan(const float* __restrict__ vIn, const float* __restrict__ kIn,
             const float* __restrict__ alpha, const double* __restrict__ cpA,
             const double* __restrict__ Csum, float* __restrict__ outp)
{
    __shared__ double sV[CHL * 64];
    const int tid = threadIdx.x;
    const int ch = blockIdx.x >> 3;
    const int b  = blockIdx.x & 7;
    #pragma unroll
    for (int q = 0; q < 8; ++q) {
        int idx = q * 256 + tid;
        int ti = idx >> 6, d = idx & 63;
        sV[idx] = (double)vIn[(((ch * CHL + ti) * BB) + b) * 64 + d];
    }
    __syncthreads();
    const int n = tid & 63;
    const int w = tid >> 6;
    double P = cpA[ch * 512 + b * 64 + n];
    size_t cb = ((size_t)ch * 8 + b) * 4096 + (size_t)w * 1024 + n;
    double C[16];
    #pragma unroll
    for (int j = 0; j < 16; ++j) C[j] = Csum[cb + j * 64];

    float* spk = outp;
    float* mem = outp + OUTHALF;
    for (int i = 0; i < CHL; ++i) {
        int t = ch * CHL + i;
        int base = (t * BB + b) * 64 + n;
        P *= (double)alpha[base];
        double invp = 1.0 / (P + EPSV);
        double kd = (double)kIn[base] * invp;
        const double* vrow = &sV[i * 64 + w * 16];
        size_t ob = ((size_t)t * BB + b) * 4096 + (size_t)w * 1024 + n;
        #pragma unroll
        for (int j = 0; j < 16; ++j) {
            C[j] = fma(vrow[j], kd, C[j]);
            double S = P * C[j];
            mem[ob + j * 64] = (float)S;
            spk[ob + j * 64] = (S > 1.0) ? 1.0f : 0.0f;
        }
    }
}

// ---------------- launch -------------------------------------------------------
extern "C" void kernel_launch(void* const* d_in, const int* in_sizes, int n_in,
                              void* d_out, int out_size, void* d_ws, size_t ws_size,
                              hipStream_t stream)
{
    const float* x  = (const float*)d_in[0];
    const float* Wv = (const float*)d_in[1];
    const float* bv = (const float*)d_in[2];
    const float* Wk = (const float*)d_in[3];
    const float* bk = (const float*)d_in[4];
    const float* Wa = (const float*)d_in[5];
    const float* ba = (const float*)d_in[6];
    float* out = (float*)d_out;

    char* ws = (char*)d_ws;
    float*  v     = (float*)(ws);                                   // 2 MB
    float*  kk    = (float*)(ws + (2u << 20));                      // 2 MB
    float*  alpha = (float*)(ws + (4u << 20));                      // 2 MB
    double* cpA   = (double*)(ws + (6u << 20));                     // 128 KB
    double* Csum  = (double*)(ws + (7u << 20));                     // 8 MB

    hipLaunchKernelGGL(k1_proj,       dim3(512), dim3(256), 0, stream,
                       x, Wv, bv, Wk, bk, Wa, ba, v, kk, alpha);
    hipLaunchKernelGGL(k2a_chunkprod, dim3(64),  dim3(256), 0, stream, alpha, cpA);
    hipLaunchKernelGGL(k2b_prefix,    dim3(1),   dim3(512), 0, stream, cpA);
    hipLaunchKernelGGL(k3_csum,       dim3(256), dim3(256), 0, stream,
                       v, kk, alpha, cpA, Csum);
    hipLaunchKernelGGL(k3b_prefix,    dim3(128), dim3(256), 0, stream, Csum);
    hipLaunchKernelGGL(k4_scan,       dim3(256), dim3(256), 0, stream,
                       v, kk, alpha, cpA, Csum, out);
}